// Round 8
// baseline (576.859 us; speedup 1.0000x reference)
//
#include <hip/hip_runtime.h>
#include <hip/hip_cooperative_groups.h>

namespace cg = cooperative_groups;

// BoostedNeuralLDPCDecoder — MI355X HIP implementation (round 8)
//
// Rounds 1-7 evidence: the multi-kernel pipeline floor is ~190us, dominated
// by 11 serialized dispatches (launch + device drain) around short latency-
// bound kernels (~35us of real work). Round 5's per-b fusion failed by using
// only 64 CUs. This round: ONE persistent cooperative kernel, 256 blocks x
// 1024 threads (1 block/CU, 16 waves/CU, all 256 CUs), grid.sync() between
// CN/VN phases (9 syncs). Per-task bodies are byte-identical to the verified
// round-7 kernels (biased-uint8 c2v, SWAR quad-z gathers) -> absmax 0.
//
// Layouts:
//   tot  [N][B][Z] float      (6.68 MB)   belief for next iteration
//   c2v  [E+1][B][Z] uint8    (9.07 MB)   biased 2*msg+32 in [2,62]; row E=0x20
//   tables (edge->vn/shift, per-VN padded gather offsets) in per-block LDS

#define ITERS 5
#define Nn 68
#define Mm 46
#define Zz 384
#define Ee 368
#define Bb 64
#define Kk 8          // edges per CN (E/M)
#define PADD 24       // padded max VN degree (verified rounds 1-7: absmax 0)
#define BIGF 1e9f

#define ROWB (Bb*Zz)                     // 24,576 B per c2v edge-row
#define TOT_ELEMS (Nn*Bb*Zz)             // 1,671,168 floats
#define C2V_BYTES ((Ee+1)*ROWB)          // 9,068,544 B (incl. dummy row)
#define TOT_OFF   0
#define C2V_OFF   (TOT_ELEMS*4)          // 6,684,672
// ws need: C2V_OFF + C2V_BYTES = 15,753,216 B (~15.8 MB)

#define GRID 256
#define BLK  1024
#define NT   (GRID*BLK)                  // 262,144 threads
#define TCN  (Mm*Bb*Zz)                  // 1,130,496 CN lane-tasks
#define TVN  (Nn*Bb*96)                  // 417,792 VN quad-z tasks

__global__ __launch_bounds__(BLK) void fused_kernel(
    const float* __restrict__ xa,        // [B][N][Z]
    const float* __restrict__ cn_weight, // [ITERS]
    const int* __restrict__ edge_vn, const int* __restrict__ edge_shift,
    float* __restrict__ out,             // [ITERS][B][Z][N]
    float* __restrict__ tot, unsigned char* __restrict__ c2v)
{
    cg::grid_group grid = cg::this_grid();
    __shared__ int s_ev[Ee], s_sh[Ee];
    __shared__ int s_deg[Nn];
    __shared__ int s_voff[Nn * PADD];

    const int tid = threadIdx.x;
    const int gid = blockIdx.x * BLK + tid;

    // ---- per-block tables (parallel across blocks, ~2us) ----
    for (int t = tid; t < Ee; t += BLK) { s_ev[t] = edge_vn[t]; s_sh[t] = edge_shift[t]; }
    if (blockIdx.x == 0) {
        // global dummy row = biased zero (0x20); first remote read is in VN0,
        // which is after the first grid.sync()
        int4* p = (int4*)(c2v + (size_t)Ee * ROWB);
        const int4 v = make_int4(0x20202020, 0x20202020, 0x20202020, 0x20202020);
        for (int i = tid; i < ROWB / 16; i += BLK) p[i] = v;
    }
    __syncthreads();
    if (tid < Nn) {
        int d = 0;
        for (int e = 0; e < Ee; e++)
            if (s_ev[e] == tid && d < PADD) s_voff[tid * PADD + (d++)] = e * ROWB;
        s_deg[tid] = d;
        for (int j = d; j < PADD; j++) s_voff[tid * PADD + j] = Ee * ROWB; // dummy
    }
    __syncthreads();

    #pragma unroll 1
    for (int it = 0; it < ITERS; it++) {
        const float w  = cn_weight[it];
        const bool sub = (it != 0);      // at it0: belief==xa, c2v==0

        // ---- CN phase: min-sum; task t = (cn, b, zc), lane = zc (coalesced) ----
        #pragma unroll 1
        for (int t = gid; t < TCN; t += NT) {
            int zc = t % Zz;
            int u  = t / Zz;
            int b  = u & 63;
            int cn = u >> 6;

            float v[Kk]; int off[Kk];
            float m1 = BIGF; unsigned sflip = 0u;
            #pragma unroll
            for (int k = 0; k < Kk; k++) {
                int e  = cn + k * Mm;            // edge_cn = e % M
                int sh = s_sh[e], n = s_ev[e];   // wave-uniform LDS broadcast
                int z  = zc - sh; z += (z >> 31) & Zz;   // mod Z
                int o  = e * ROWB + b * Zz + z;
                off[k] = o;
                float x;
                if (sub) {
                    x = tot[(n * Bb + b) * Zz + z]
                        - 0.5f * (float)((int)c2v[o] - 32);  // exact decode
                } else {
                    x = xa[(b * Nn + n) * Zz + z];
                }
                x = fminf(20.0f, fmaxf(-20.0f, x));          // allowed_llr_range
                v[k] = x;
                if (x < 0.0f) sflip ^= 1u;
                m1 = fminf(m1, fabsf(x));
            }
            float m2 = BIGF;                     // ref tie semantics
            #pragma unroll
            for (int k = 0; k < Kk; k++) {
                float mag = fabsf(v[k]);
                if (mag != m1) m2 = fminf(m2, mag);
            }
            #pragma unroll
            for (int k = 0; k < Kk; k++) {
                float mag  = fabsf(v[k]);
                float emin = (mag == m1) ? m2 : m1;
                unsigned neg = sflip ^ ((v[k] < 0.0f) ? 1u : 0u);
                float ext = neg ? -emin : emin;
                // _qms5(w*ext): forward == clip(rintf(2x)/2, +-7.5); biased 2q
                float r = rintf(w * ext * 2.0f);
                r = fminf(15.0f, fmaxf(-15.0f, r));
                c2v[off[k]] = (unsigned char)((int)r + 32);
            }
        }

        grid.sync();                             // CN writes -> VN reads

        // ---- VN phase: quad-z SWAR gather; task t = (n, b, q), lane~q ----
        float* outp = out + (size_t)it * ((size_t)Bb * Nn * Zz);
        #pragma unroll 1
        for (int t = gid; t < TVN; t += NT) {
            int q = t % 96;
            int u = t / 96;
            int b = u & 63;
            int n = u >> 6;
            int z = q * 4;                       // owns z..z+3 (dword-aligned)
            int d = s_deg[n];
            const int* vo = s_voff + n * PADD;
            int base = b * Zz + z;
            // SWAR: two 2x16-bit accumulators; bytes biased (2m+32); exact
            unsigned ae = 0u, ao = 0u;           // ae: z,z+2 ; ao: z+1,z+3
            #pragma unroll
            for (int j = 0; j < 8; j++) {
                unsigned uu = *(const unsigned*)(c2v + (vo[j] + base));
                ae += uu & 0x00FF00FFu;
                ao += (uu >> 8) & 0x00FF00FFu;
            }
            int L = 8;
            if (d > 8) {
                L = 16;
                #pragma unroll
                for (int j = 8; j < 16; j++) {
                    unsigned uu = *(const unsigned*)(c2v + (vo[j] + base));
                    ae += uu & 0x00FF00FFu;
                    ao += (uu >> 8) & 0x00FF00FFu;
                }
                if (d > 16) {
                    L = 24;
                    #pragma unroll
                    for (int j = 16; j < PADD; j++) {
                        unsigned uu = *(const unsigned*)(c2v + (vo[j] + base));
                        ae += uu & 0x00FF00FFu;
                        ao += (uu >> 8) & 0x00FF00FFu;
                    }
                }
            }
            int bias = 32 * L;                   // dummy rows contribute exactly bias
            float4 x = *(const float4*)(xa + (size_t)(b * Nn + n) * Zz + z);
            float s0 = x.x + 0.5f * (float)((int)(ae & 0xFFFFu) - bias);
            float s1 = x.y + 0.5f * (float)((int)(ao & 0xFFFFu) - bias);
            float s2 = x.z + 0.5f * (float)((int)(ae >> 16) - bias);
            float s3 = x.w + 0.5f * (float)((int)(ao >> 16) - bias);
            if (it < ITERS - 1)
                *(float4*)(tot + (n * Bb + b) * Zz + z) = make_float4(s0, s1, s2, s3);
            float* op = outp + ((size_t)b * Zz + z) * Nn + n;
            op[0] = s0; op[Nn] = s1; op[2 * Nn] = s2; op[3 * Nn] = s3;
        }

        if (it < ITERS - 1) grid.sync();         // VN writes -> next CN reads
    }
}

extern "C" void kernel_launch(void* const* d_in, const int* in_sizes, int n_in,
                              void* d_out, int out_size, void* d_ws, size_t ws_size,
                              hipStream_t stream) {
    const float* xa        = (const float*)d_in[0];  // [B][N][Z]
    const float* cn_weight = (const float*)d_in[1];  // [ITERS]
    const int*   edge_vn   = (const int*)d_in[2];    // [E]
    // d_in[3] = edge_cn: structurally e % M, not needed
    const int*   edge_shift= (const int*)d_in[4];    // [E]
    float* out = (float*)d_out;                      // [ITERS][B][Z][N]

    char* ws = (char*)d_ws;
    float*         tot = (float*)(ws + TOT_OFF);
    unsigned char* c2v = (unsigned char*)(ws + C2V_OFF);

    void* args[] = {(void*)&xa, (void*)&cn_weight, (void*)&edge_vn,
                    (void*)&edge_shift, (void*)&out, (void*)&tot, (void*)&c2v};
    hipLaunchCooperativeKernel((void*)fused_kernel, dim3(GRID), dim3(BLK),
                               args, 0, stream);
}

// Round 9
// 310.525 us; speedup vs baseline: 1.8577x; 1.8577x over previous
//
#include <hip/hip_runtime.h>

// BoostedNeuralLDPCDecoder — MI355X HIP implementation (round 9)
//
// ONE regular kernel, 64 blocks (one per batch b) x 1024 threads, all 5
// iterations internal with __syncthreads() between phases. Key idea vs the
// failed r5 fusion: the per-b belief array tot[N][Z] is 104KB -> lives in LDS
// for the whole kernel (gfx950 has 160KB/CU). Global tot disappears; CN's
// belief gather is ds_read (conflict-free, odd stride 385); out(it) is a
// straight LDS->global contiguous copy of s_tot (out(it)[z][n] ==
// belief(it+1)[n][z]), overlapped with the next CN phase. Each block pins to
// one CU -> its 141KB c2v slice stays in its XCD's L2 all 5 iterations.
// Phases/iter: P1 = CN(it) + out-copy(it-1)  |  P2 = VN(it). 11 barriers.
//
// Per-element math byte-identical to verified rounds 6-8 (biased-uint8 c2v,
// SWAR quad-z dword gathers, exact half-integer sums, ref tie semantics,
// rintf==round-half-even, _qms5 forward == clip(rintf(2x)/2,±7.5)) -> absmax 0.

#define ITERS 5
#define Nn 68
#define Mm 46
#define Zz 384
#define Ee 368
#define Bb 64
#define Kk 8            // edges per CN (E/M)
#define PADD 24         // padded max VN degree (verified rounds 1-8: absmax 0)
#define BIGF 1e9f
#define PAD 385         // LDS row stride, odd -> conflict-free for all phases

#define NZ     (Nn*Zz)      // 26112 elems per (b) belief slice
#define SLICE  (Ee*Zz)      // 141312 B: dummy-row offset within a b's c2v slice
#define SLICEP ((Ee+1)*Zz)  // 141696 B per-b c2v slice (incl. dummy row)
#define TCN    (Mm*Zz)      // 17664 CN lane-tasks per b
#define TOC    NZ           // 26112 out-copy dword tasks per b
#define TVN    (Nn*96)      // 6528 VN quad-z tasks per b
// ws need: Bb*SLICEP = 9,068,544 B

__global__ __launch_bounds__(1024) void decode_kernel(
    const float* __restrict__ xa,        // [B][N][Z]
    const float* __restrict__ cn_weight, // [ITERS]
    const int* __restrict__ edge_vn, const int* __restrict__ edge_shift,
    float* __restrict__ out,             // [ITERS][B][Z][N]
    unsigned char* __restrict__ c2v_g)   // [B][E+1][Z] biased 2*msg+32
{
    __shared__ float s_tot[Nn * PAD];    // 104,720 B belief (resident all iters)
    __shared__ int   s_ev[Ee], s_sh[Ee];
    __shared__ int   s_deg[Nn];
    __shared__ int   s_voff[Nn * PADD];  // per-VN byte offsets; dummy = SLICE

    const int b   = blockIdx.x;
    const int tid = threadIdx.x;
    const float* xa_b = xa + (size_t)b * NZ;
    unsigned char* c2v_b = c2v_g + (size_t)b * SLICEP;

    // ---- preamble: tables (LDS atomics), xa -> s_tot, dummy row = 0x20 ----
    if (tid < Ee) { s_ev[tid] = edge_vn[tid]; s_sh[tid] = edge_shift[tid]; }
    else if (tid < Ee + Nn) s_deg[tid - Ee] = 0;
    __syncthreads();
    if (tid < Ee) {
        int n = s_ev[tid];
        int slot = atomicAdd(&s_deg[n], 1);          // slot order irrelevant:
        if (slot < PADD) s_voff[n * PADD + slot] = tid * Zz;  // int sums exact
    }
    for (int t = tid; t < TVN; t += 1024) {          // xa quad -> s_tot
        int n = t / 96, z = (t - n * 96) * 4;
        float4 v = *(const float4*)(xa_b + n * Zz + z);
        float* p = s_tot + n * PAD + z;
        p[0] = v.x; p[1] = v.y; p[2] = v.z; p[3] = v.w;
    }
    if (tid < Zz / 4)                                // biased-zero dummy row
        ((unsigned*)(c2v_b + SLICE))[tid] = 0x20202020u;
    __syncthreads();
    if (tid < Nn) {
        int d = s_deg[tid];
        if (d > PADD) { d = PADD; s_deg[tid] = PADD; }
        for (int j = d; j < PADD; j++) s_voff[tid * PADD + j] = SLICE;
    }
    __syncthreads();

    #pragma unroll 1
    for (int it = 0; it < ITERS; it++) {
        const float w = cn_weight[it];
        // ---- P1: CN(it) min-sum + out-copy(it-1) (both read-only on s_tot) ----
        const int T1 = TCN + (it ? TOC : 0);
        float* out_prev = out + (size_t)(it - 1) * ((size_t)Bb * NZ) + (size_t)b * NZ;
        #pragma unroll 1
        for (int t = tid; t < T1; t += 1024) {
            if (t < TCN) {
                int cn = t / Zz;                     // wave-uniform (384 = 6 waves)
                int zc = t - cn * Zz;                // CN-domain lifted row
                float v[Kk]; int off[Kk];
                float m1 = BIGF; unsigned sflip = 0u;
                #pragma unroll
                for (int k = 0; k < Kk; k++) {
                    int e  = cn + k * Mm;            // edge_cn = e % M
                    int sh = s_sh[e], n = s_ev[e];   // LDS broadcast
                    int z  = zc - sh; z += (z >> 31) & Zz;   // mod Z
                    int o  = e * Zz + z;
                    off[k] = o;
                    float x = s_tot[n * PAD + z];    // belief gather from LDS
                    if (it) x -= 0.5f * (float)((int)c2v_b[o] - 32); // exact decode
                    x = fminf(20.0f, fmaxf(-20.0f, x));              // llr clip
                    v[k] = x;
                    if (x < 0.0f) sflip ^= 1u;
                    m1 = fminf(m1, fabsf(x));
                }
                float m2 = BIGF;                     // ref tie semantics
                #pragma unroll
                for (int k = 0; k < Kk; k++) {
                    float mag = fabsf(v[k]);
                    if (mag != m1) m2 = fminf(m2, mag);
                }
                #pragma unroll
                for (int k = 0; k < Kk; k++) {
                    float mag  = fabsf(v[k]);
                    float emin = (mag == m1) ? m2 : m1;
                    unsigned neg = sflip ^ ((v[k] < 0.0f) ? 1u : 0u);
                    float ext = neg ? -emin : emin;
                    // _qms5(w*ext): forward == clip(rintf(2x)/2, ±7.5); biased 2q
                    float r = rintf(w * ext * 2.0f);
                    r = fminf(15.0f, fmaxf(-15.0f, r));
                    c2v_b[off[k]] = (unsigned char)((int)r + 32);
                }
            } else {
                // out(it-1)[b][z][n] == s_tot[n][z]; j linear -> coalesced store
                int j = t - TCN;
                int z = j / Nn, n = j - z * Nn;      // lanes: consecutive n
                out_prev[j] = s_tot[n * PAD + z];    // bank = (n+z)%32: conflict-free
            }
        }
        __syncthreads();                             // CN c2v writes -> VN reads

        // ---- P2: VN(it): SWAR quad-z gather -> s_tot (new belief) ----
        #pragma unroll 1
        for (int t = tid; t < TVN; t += 1024) {
            int n = t / 96, z = (t - n * 96) * 4;    // owns z..z+3, dword-aligned
            int d = s_deg[n];
            const int* vo = s_voff + n * PADD;
            // SWAR: two 2x16-bit accumulators; bytes biased (2m+32); exact
            unsigned ae = 0u, ao = 0u;               // ae: z,z+2 ; ao: z+1,z+3
            #pragma unroll
            for (int j = 0; j < 8; j++) {
                unsigned uu = *(const unsigned*)(c2v_b + vo[j] + z);
                ae += uu & 0x00FF00FFu;
                ao += (uu >> 8) & 0x00FF00FFu;
            }
            int L = 8;
            if (d > 8) {
                L = 16;
                #pragma unroll
                for (int j = 8; j < 16; j++) {
                    unsigned uu = *(const unsigned*)(c2v_b + vo[j] + z);
                    ae += uu & 0x00FF00FFu;
                    ao += (uu >> 8) & 0x00FF00FFu;
                }
                if (d > 16) {
                    L = 24;
                    #pragma unroll
                    for (int j = 16; j < PADD; j++) {
                        unsigned uu = *(const unsigned*)(c2v_b + vo[j] + z);
                        ae += uu & 0x00FF00FFu;
                        ao += (uu >> 8) & 0x00FF00FFu;
                    }
                }
            }
            int bias = 32 * L;                       // dummies contribute exactly bias
            float4 x4 = *(const float4*)(xa_b + n * Zz + z);
            float* p = s_tot + n * PAD + z;
            p[0] = x4.x + 0.5f * (float)((int)(ae & 0xFFFFu) - bias);
            p[1] = x4.y + 0.5f * (float)((int)(ao & 0xFFFFu) - bias);
            p[2] = x4.z + 0.5f * (float)((int)(ae >> 16) - bias);
            p[3] = x4.w + 0.5f * (float)((int)(ao >> 16) - bias);
        }
        __syncthreads();                             // VN s_tot -> next CN / OC
    }

    // ---- final out-copy for it = ITERS-1 ----
    float* out_last = out + (size_t)(ITERS - 1) * ((size_t)Bb * NZ) + (size_t)b * NZ;
    for (int j = tid; j < TOC; j += 1024) {
        int z = j / Nn, n = j - z * Nn;
        out_last[j] = s_tot[n * PAD + z];
    }
}

extern "C" void kernel_launch(void* const* d_in, const int* in_sizes, int n_in,
                              void* d_out, int out_size, void* d_ws, size_t ws_size,
                              hipStream_t stream) {
    const float* xa        = (const float*)d_in[0];  // [B][N][Z]
    const float* cn_weight = (const float*)d_in[1];  // [ITERS]
    const int*   edge_vn   = (const int*)d_in[2];    // [E]
    // d_in[3] = edge_cn: structurally e % M, not needed
    const int*   edge_shift= (const int*)d_in[4];    // [E]
    float* out = (float*)d_out;                      // [ITERS][B][Z][N]

    unsigned char* c2v = (unsigned char*)d_ws;       // [B][E+1][Z]

    decode_kernel<<<Bb, 1024, 0, stream>>>(xa, cn_weight, edge_vn, edge_shift,
                                           out, c2v);
}